// Round 8
// baseline (273.142 us; speedup 1.0000x reference)
//
#include <hip/hip_runtime.h>

#define SEQ    2048
#define DMODEL 512
#define NHEAD  8
#define HDIM   64
#define BATCH  4
#define NROWS  65536          // H*SEQ*BATCH scrambled q-rows
#define KSPLIT 2

#define LOG2E  1.4426950408889634f
#define QSCALE 0.18033688011112042f   // 0.125 * log2(e), folded into Q proj

typedef float f32x4  __attribute__((ext_vector_type(4)));
typedef float f32x16 __attribute__((ext_vector_type(16)));
typedef _Float16 h16x8 __attribute__((ext_vector_type(8)));
typedef _Float16 h16x2 __attribute__((ext_vector_type(2)));

union U4H { uint4 u; h16x8 h; };
union U1H2 { unsigned int u; h16x2 h; };

static __device__ inline h16x2 pkrtz(float a, float b) {
    return __builtin_bit_cast(h16x2, __builtin_amdgcn_cvt_pkrtz(a, b));
}
static __device__ inline unsigned short f2h(float x) {
    _Float16 h = (_Float16)x;
    return __builtin_bit_cast(unsigned short, h);
}
// async 16B/lane global->LDS copy (lds base must be wave-uniform, 16B aligned)
static __device__ inline void async_cp16(const void* g, void* l) {
    __builtin_amdgcn_global_load_lds(
        (const __attribute__((address_space(1))) unsigned int*)g,
        (__attribute__((address_space(3))) unsigned int*)l,
        16, 0, 0);
}

// ---------------------------------------------------------------------------
// Transpose-cast the four 512x512 weight matrices: W[k][n] -> Wt[n][k] fp16
// ---------------------------------------------------------------------------
__global__ __launch_bounds__(256) void transpose_cast_w(
    const float* __restrict__ s0, const float* __restrict__ s1,
    const float* __restrict__ s2, const float* __restrict__ s3,
    unsigned short* __restrict__ d0, unsigned short* __restrict__ d1,
    unsigned short* __restrict__ d2, unsigned short* __restrict__ d3)
{
    const float* S; unsigned short* D;
    switch (blockIdx.z) {
        case 0: S = s0; D = d0; break;
        case 1: S = s1; D = d1; break;
        case 2: S = s2; D = d2; break;
        default: S = s3; D = d3; break;
    }
    __shared__ float T[32][33];
    const int t = threadIdx.x;
    const int r = t >> 3, c = (t & 7) * 4;
    const int k0 = blockIdx.x * 32, n0 = blockIdx.y * 32;
    float4 v = *(const float4*)&S[(size_t)(k0 + r) * DMODEL + n0 + c];
    T[r][c] = v.x; T[r][c + 1] = v.y; T[r][c + 2] = v.z; T[r][c + 3] = v.w;
    __syncthreads();
    ushort4 o;
    o.x = f2h(T[c + 0][r]); o.y = f2h(T[c + 1][r]);
    o.z = f2h(T[c + 2][r]); o.w = f2h(T[c + 3][r]);
    *(ushort4*)&D[(size_t)(n0 + r) * DMODEL + k0 + c] = o;
}

// ---------------------------------------------------------------------------
// Mask pre-pass (wave-coalesced): em = fp16(exp(mask)) in permuted layout
// em[(kt*SEQ+q)*64 + hl*32 + mt*16 + g*4 + r] for k = kt*64+32mt+8g+4hl+r.
// 16 lanes cover one (kt,q) 64-elem row -> 128B contiguous writes.
// grid (SEQ/64, SEQ/16), 256 thr.
// ---------------------------------------------------------------------------
__global__ __launch_bounds__(256) void prep_mask(
    const float* __restrict__ mask, unsigned short* __restrict__ mp)
{
    const int t = threadIdx.x;
    const int kt = blockIdx.x;
    const int q  = blockIdx.y * 16 + (t >> 4);
    const int l  = t & 15;
    const int hl = l >> 3, mt = (l >> 2) & 1, g = l & 3;
    const int f4 = kt * 16 + 8 * mt + 2 * g + hl;   // float4 index in row
    float4 v = ((const float4*)mask)[(size_t)q * (SEQ / 4) + f4];
    U1H2 lo, hi;
    lo.h = pkrtz(__builtin_amdgcn_exp2f(v.x * LOG2E),
                 __builtin_amdgcn_exp2f(v.y * LOG2E));
    hi.h = pkrtz(__builtin_amdgcn_exp2f(v.z * LOG2E),
                 __builtin_amdgcn_exp2f(v.w * LOG2E));
    *(uint2*)&mp[((size_t)kt * SEQ + q) * 64 + l * 4] = make_uint2(lo.u, hi.u);
}

// ---------------------------------------------------------------------------
// GEMM: C[M][512] = A[M][512] @ Wt[512][512]^T + bias (Wt is [n][k]).
// BMx128 tile, BK=32, 256 thr = 4 waves (2x2), wave = (BM/2)m x 64n.
// Double-buffered, ONE barrier per K-iter. LDS chunk-major padded:
// [kquad][row][8] with chunk stride 1032 hw (2064B) -> bank = 4*(q+row),
// conflict-free frag reads; async instr = one chunk-half (64 rows x 16B).
// A_FP32: A prefetched to regs, cvt+stored after MFMAs (fused cast).
// EPI: 0 f32 row-major, 1 f16 row-major (*oscale), 2 f16 per-head transposed.
// ---------------------------------------------------------------------------
template <int A_FP32, int EPI, int BM>
static __device__ inline void gemm_core(
    const void* __restrict__ Ap, const unsigned short* __restrict__ Bt,
    const float* __restrict__ bias, void* __restrict__ Cout, float oscale,
    int bm, int bn)
{
    const int ACS = BM * 8 + 8;                 // chunk stride (halfwords)
    const int MT  = BM / 32;                    // m-tiles of 16 per wave
    __shared__ __align__(16) unsigned short As[2][4 * (BM * 8 + 8)];
    __shared__ __align__(16) unsigned short Bs[2][4 * 1032];

    const int t = threadIdx.x;
    const int lane = t & 63, w = t >> 6;
    const int wm = w >> 1, wn = w & 1;
    const int c = lane & 15, quad = lane >> 4;

    const unsigned short* Ab = (const unsigned short*)Ap;
    const float* Af = (const float*)Ap;

    f32x4 acc[MT][4] = {};
    float4 areg[BM / 32];

    // ---- stage tile 0 ----
    if (A_FP32) {
        #pragma unroll
        for (int p = 0; p < BM / 32; p++) {
            int cid = p * 256 + t;
            int row = cid >> 3, fc4 = cid & 7;
            float4 av = *(const float4*)&Af[(size_t)(bm + row) * DMODEL + fc4 * 4];
            U1H2 lo, hi;
            lo.h = pkrtz(av.x, av.y); hi.h = pkrtz(av.z, av.w);
            *(uint2*)&As[0][(fc4 >> 1) * ACS + row * 8 + (fc4 & 1) * 4] =
                make_uint2(lo.u, hi.u);
        }
    } else {
        #pragma unroll
        for (int h = 0; h < BM / 64; h++) {
            int row = h * 64 + lane;
            async_cp16(&Ab[(size_t)(bm + row) * DMODEL + w * 8],
                       &As[0][w * ACS + h * 512]);
        }
    }
    #pragma unroll
    for (int h = 0; h < 2; h++) {
        int row = h * 64 + lane;
        async_cp16(&Bt[(size_t)(bn + row) * DMODEL + w * 8],
                   &Bs[0][w * 1032 + h * 512]);
    }

    for (int kt = 0; kt < DMODEL / 32; kt++) {
        const int p = kt & 1;
        __syncthreads();   // buf p staged (own vmcnt drained), buf p^1 free

        const int kn = (kt + 1) * 32;
        if (kt + 1 < DMODEL / 32) {
            if (A_FP32) {
                #pragma unroll
                for (int pp = 0; pp < BM / 32; pp++) {
                    int cid = pp * 256 + t;
                    int row = cid >> 3, fc4 = cid & 7;
                    areg[pp] = *(const float4*)&Af[(size_t)(bm + row) * DMODEL + kn + fc4 * 4];
                }
            } else {
                #pragma unroll
                for (int h = 0; h < BM / 64; h++) {
                    int row = h * 64 + lane;
                    async_cp16(&Ab[(size_t)(bm + row) * DMODEL + kn + w * 8],
                               &As[p ^ 1][w * ACS + h * 512]);
                }
            }
            #pragma unroll
            for (int h = 0; h < 2; h++) {
                int row = h * 64 + lane;
                async_cp16(&Bt[(size_t)(bn + row) * DMODEL + kn + w * 8],
                           &Bs[p ^ 1][w * 1032 + h * 512]);
            }
        }

        U4H af[MT], bf[4];
        #pragma unroll
        for (int mt = 0; mt < MT; mt++)
            af[mt].u = *(const uint4*)&As[p][quad * ACS + (wm * (BM / 2) + mt * 16 + c) * 8];
        #pragma unroll
        for (int nt = 0; nt < 4; nt++)
            bf[nt].u = *(const uint4*)&Bs[p][quad * 1032 + (wn * 64 + nt * 16 + c) * 8];
        #pragma unroll
        for (int mt = 0; mt < MT; mt++)
            #pragma unroll
            for (int nt = 0; nt < 4; nt++)
                acc[mt][nt] = __builtin_amdgcn_mfma_f32_16x16x32_f16(
                    af[mt].h, bf[nt].h, acc[mt][nt], 0, 0, 0);

        if (A_FP32 && kt + 1 < DMODEL / 32) {
            #pragma unroll
            for (int pp = 0; pp < BM / 32; pp++) {
                int cid = pp * 256 + t;
                int row = cid >> 3, fc4 = cid & 7;
                U1H2 lo, hi;
                lo.h = pkrtz(areg[pp].x, areg[pp].y);
                hi.h = pkrtz(areg[pp].z, areg[pp].w);
                *(uint2*)&As[p ^ 1][(fc4 >> 1) * ACS + row * 8 + (fc4 & 1) * 4] =
                    make_uint2(lo.u, hi.u);
            }
        }
    }

    if (EPI == 2) {
        // transposed per-head write: vT[((b*8+h)*64+dv)*SEQ + key]
        #pragma unroll
        for (int nt = 0; nt < 4; nt++) {
            int ng = bn + wn * 64 + nt * 16 + c;
            int h = ng >> 6, dv = ng & 63;
            float bv = bias[ng];
            #pragma unroll
            for (int mt = 0; mt < MT; mt++) {
                int mg0 = bm + wm * (BM / 2) + mt * 16 + quad * 4;
                int bb = mg0 >> 11, key0 = mg0 & (SEQ - 1);
                U1H2 lo, hi;
                lo.h = pkrtz(acc[mt][nt][0] + bv, acc[mt][nt][1] + bv);
                hi.h = pkrtz(acc[mt][nt][2] + bv, acc[mt][nt][3] + bv);
                *(uint2*)&((unsigned short*)Cout)[
                    ((size_t)(bb * NHEAD + h) * HDIM + dv) * SEQ + key0] =
                    make_uint2(lo.u, hi.u);
            }
        }
        return;
    }
    #pragma unroll
    for (int nt = 0; nt < 4; nt++) {
        int ng = bn + wn * 64 + nt * 16 + c;
        float bv = bias[ng];
        #pragma unroll
        for (int mt = 0; mt < MT; mt++) {
            #pragma unroll
            for (int r = 0; r < 4; r++) {
                int mg = bm + wm * (BM / 2) + mt * 16 + quad * 4 + r;
                float v = (acc[mt][nt][r] + bv) * oscale;
                if (EPI == 1)
                    ((unsigned short*)Cout)[(size_t)mg * DMODEL + ng] = f2h(v);
                else
                    ((float*)Cout)[(size_t)mg * DMODEL + ng] = v;
            }
        }
    }
}

struct QKVArgs {
    const float *A0, *A1, *A2;
    const unsigned short *W0, *W1, *W2;
    const float *b0, *b1, *b2;
    unsigned short *o0, *o1, *o2;
};

__global__ __launch_bounds__(256, 2) void gemm_qkv(QKVArgs a) {
    if (blockIdx.z == 2)
        gemm_core<1, 2, 128>(a.A2, a.W2, a.b2, a.o2, 1.0f, blockIdx.y * 128, blockIdx.x * 128);
    else if (blockIdx.z == 1)
        gemm_core<1, 1, 128>(a.A1, a.W1, a.b1, a.o1, 1.0f, blockIdx.y * 128, blockIdx.x * 128);
    else
        gemm_core<1, 1, 128>(a.A0, a.W0, a.b0, a.o0, QSCALE, blockIdx.y * 128, blockIdx.x * 128);
}

__global__ __launch_bounds__(256, 3) void gemm_fin(
    const unsigned short* __restrict__ A, const unsigned short* __restrict__ W,
    const float* __restrict__ bias, float* __restrict__ C) {
    gemm_core<0, 0, 64>(A, W, bias, C, 1.0f, blockIdx.y * 64, blockIdx.x * 128);
}

// ---------------------------------------------------------------------------
// Flash attention, 32x32x16 f16 MFMA, S^T trick, no-max softmax, K-SPLIT.
// Double-buffered global_load_lds staging into PADDED CHUNK-MAJOR LDS
// ([chunk][65 rows][8] halfwords, chunk stride 1040B): one async instr = one
// chunk's 64 rows (1024B contiguous); frag reads bank = 4*(fc+row) mod 32 —
// the layout that measured ZERO conflicts in round 6. ONE barrier per K-tile.
// ---------------------------------------------------------------------------
__global__ __launch_bounds__(256, 3) void attn6(
    const unsigned short* __restrict__ qb, const unsigned short* __restrict__ kb,
    const unsigned short* __restrict__ vT, const unsigned short* __restrict__ emp,
    unsigned short* __restrict__ Xp, float* __restrict__ Lp)
{
    __shared__ __align__(16) unsigned short KV[2][2][8 * 520];  // [buf][K/V]

    const int t = threadIdx.x;            // 0..255
    const int lane = t & 63, w = t >> 6;  // 4 waves
    const int c32 = lane & 31, hl = lane >> 5;
    const int bh = blockIdx.x, b = bh >> 3, head = bh & 7;
    const int q0 = blockIdx.y * 128;
    const int split = blockIdx.z;         // keys [split*1024, +1024)
    const int qg = q0 + w * 32 + c32;
    const int NT = (SEQ / KSPLIT) / 64;   // 16 K-tiles per split

    // hoisted Q B-frags (q pre-scaled by 0.125*log2e in projection)
    const unsigned short* qrow = qb + ((size_t)b * SEQ + qg) * DMODEL + head * HDIM;
    U4H Qf[4];
    #pragma unroll
    for (int s = 0; s < 4; s++)
        Qf[s].u = *(const uint4*)&qrow[s * 16 + hl * 8];

    const unsigned short* kgb = kb + (size_t)b * SEQ * DMODEL + head * HDIM
                              + (size_t)split * (SEQ / KSPLIT) * DMODEL;
    const unsigned short* vgb = vT + (size_t)bh * HDIM * SEQ + split * (SEQ / KSPLIT);

    // stage tile 0 into buf 0: wave w stages chunks 2w, 2w+1 of K and V
    #pragma unroll
    for (int i = 0; i < 2; i++) {
        int fc = 2 * w + i;
        async_cp16(&kgb[(size_t)lane * DMODEL + fc * 8], &KV[0][0][fc * 520]);
        async_cp16(&vgb[(size_t)lane * SEQ + fc * 8],    &KV[0][1][fc * 520]);
    }

    f32x16 O0 = {}, O1 = {};
    float lsum = 0.f;

    for (int kt = 0; kt < NT; kt++) {
        const int p = kt & 1;
        __syncthreads();                  // buf p staged; buf p^1 reads done

        // em loads (consumed this iter)
        const int ktg = split * NT + kt;
        const unsigned short* mrow = emp + ((size_t)ktg * SEQ + qg) * 64 + hl * 32;
        U4H e0, e1, e2, e3;
        e0.u = *(const uint4*)&mrow[0];
        e1.u = *(const uint4*)&mrow[8];
        e2.u = *(const uint4*)&mrow[16];
        e3.u = *(const uint4*)&mrow[24];

        // async stage tile kt+1 into buf p^1 (in flight during compute)
        if (kt + 1 < NT) {
            int k0n = (kt + 1) * 64;
            #pragma unroll
            for (int i = 0; i < 2; i++) {
                int fc = 2 * w + i;
                async_cp16(&kgb[(size_t)(k0n + lane) * DMODEL + fc * 8],
                           &KV[p ^ 1][0][fc * 520]);
                async_cp16(&vgb[(size_t)lane * SEQ + k0n + fc * 8],
                           &KV[p ^ 1][1][fc * 520]);
            }
        }

        const unsigned short* Kp = KV[p][0];
        const unsigned short* Vp = KV[p][1];

        // ---- S^T = K.Q^T : 2 key-tiles x 4 feature-steps ----
        f32x16 S0 = {}, S1 = {};
        #pragma unroll
        for (int s = 0; s < 4; s++) {
            int fc = 2 * s + hl;
            U4H ka0, ka1;
            ka0.u = *(const uint4*)&Kp[(fc * 65 + c32) * 8];
            ka1.u = *(const uint4*)&Kp[(fc * 65 + 32 + c32) * 8];
            S0 = __builtin_amdgcn_mfma_f32_32x32x16_f16(ka0.h, Qf[s].h, S0, 0, 0, 0);
            S1 = __builtin_amdgcn_mfma_f32_32x32x16_f16(ka1.h, Qf[s].h, S1, 0, 0, 0);
        }

        // ---- softmax: p = exp2(S) * em, f16 pack, l-accumulate ----
        unsigned int Pf[4][4];
        #pragma unroll
        for (int mt = 0; mt < 2; mt++) {
            f32x16 S = mt ? S1 : S0;
            h16x8 ea = (mt ? e2 : e0).h;
            h16x8 eb = (mt ? e3 : e1).h;
            unsigned int u[4][2];
            #pragma unroll
            for (int jj = 0; jj < 8; jj++) {
                _Float16 exl = (jj < 4) ? ea[2 * jj]     : eb[2 * jj - 8];
                _Float16 exh = (jj < 4) ? ea[2 * jj + 1] : eb[2 * jj - 7];
                h16x2 ex = {exl, exh};
                h16x2 pk = pkrtz(__builtin_amdgcn_exp2f(S[2 * jj]),
                                 __builtin_amdgcn_exp2f(S[2 * jj + 1]));
                h16x2 pp = pk * ex;
                lsum += (float)pp[0] + (float)pp[1];
                u[jj >> 1][jj & 1] = __builtin_bit_cast(unsigned int, pp);
            }
            // half-wave block exchange (C-layout -> PV B-operand layout)
            unsigned int sA0 = hl ? u[0][0] : u[1][0];
            unsigned int sA1 = hl ? u[0][1] : u[1][1];
            unsigned int sB0 = hl ? u[2][0] : u[3][0];
            unsigned int sB1 = hl ? u[2][1] : u[3][1];
            unsigned int rA0 = (unsigned)__shfl_xor((int)sA0, 32, 64);
            unsigned int rA1 = (unsigned)__shfl_xor((int)sA1, 32, 64);
            unsigned int rB0 = (unsigned)__shfl_xor((int)sB0, 32, 64);
            unsigned int rB1 = (unsigned)__shfl_xor((int)sB1, 32, 64);
            Pf[2 * mt + 0][0] = hl ? rA0 : u[0][0];
            Pf[2 * mt + 0][1] = hl ? rA1 : u[0][1];
            Pf[2 * mt + 0][2] = hl ? u[1][0] : rA0;
            Pf[2 * mt + 0][3] = hl ? u[1][1] : rA1;
            Pf[2 * mt + 1][0] = hl ? rB0 : u[2][0];
            Pf[2 * mt + 1][1] = hl ? rB1 : u[2][1];
            Pf[2 * mt + 1][2] = hl ? u[3][0] : rB0;
            Pf[2 * mt + 1][3] = hl ? u[3][1] : rB1;
        }

        // ---- O^T += V^T . P : 2 dv-tiles x 4 key-steps ----
        #pragma unroll
        for (int s = 0; s < 4; s++) {
            int kc = 2 * s + hl;
            U4H va0, va1, pu;
            va0.u = *(const uint4*)&Vp[(kc * 65 + c32) * 8];
            va1.u = *(const uint4*)&Vp[(kc * 65 + 32 + c32) * 8];
            pu.u = make_uint4(Pf[s][0], Pf[s][1], Pf[s][2], Pf[s][3]);
            O0 = __builtin_amdgcn_mfma_f32_32x32x16_f16(va0.h, pu.h, O0, 0, 0, 0);
            O1 = __builtin_amdgcn_mfma_f32_32x32x16_f16(va1.h, pu.h, O1, 0, 0, 0);
        }
    }

    // ---- epilogue: combine lane-halves' l, store UNNORMALIZED f16 partial ----
    lsum += __shfl_xor(lsum, 32, 64);
    const size_t j = ((size_t)head * SEQ + qg) * BATCH + b;
    unsigned short* xr = Xp + ((size_t)split * NROWS + j) * HDIM;
    #pragma unroll
    for (int mt = 0; mt < 2; mt++) {
        f32x16 Ov = mt ? O1 : O0;
        #pragma unroll
        for (int g = 0; g < 4; g++) {
            U1H2 lo, hi;
            lo.h = pkrtz(Ov[g * 4 + 0], Ov[g * 4 + 1]);
            hi.h = pkrtz(Ov[g * 4 + 2], Ov[g * 4 + 3]);
            uint2 st = make_uint2(lo.u, hi.u);
            *(uint2*)&xr[mt * 32 + 8 * g + 4 * hl] = st;
        }
    }
    if (hl == 0) Lp[split * NROWS + j] = lsum;
}

// ---------------------------------------------------------------------------
// Combine K-split partials: xb[j][dv] = (Sum_r Xp[r][j][dv]) / (Sum_r L[r][j])
// ---------------------------------------------------------------------------
__global__ __launch_bounds__(256) void combine_attn(
    const unsigned short* __restrict__ Xp, const float* __restrict__ Lp,
    unsigned short* __restrict__ xb)
{
    int i = blockIdx.x * 256 + threadIdx.x;
    int j = i >> 3, dc = (i & 7) * 8;
    U4H a, b;
    a.u = *(const uint4*)&Xp[(size_t)j * HDIM + dc];
    b.u = *(const uint4*)&Xp[((size_t)NROWS + j) * HDIM + dc];
    float inv = 1.0f / (Lp[j] + Lp[NROWS + j]);
    U4H o;
    #pragma unroll
    for (int p = 0; p < 4; p++) {
        float s0 = ((float)a.h[2 * p]     + (float)b.h[2 * p])     * inv;
        float s1 = ((float)a.h[2 * p + 1] + (float)b.h[2 * p + 1]) * inv;
        h16x2 pk = pkrtz(s0, s1);
        o.h[2 * p] = pk[0]; o.h[2 * p + 1] = pk[1];
    }
    *(uint4*)&xb[(size_t)j * HDIM + dc] = o.u;
}

// ---------------------------------------------------------------------------
extern "C" void kernel_launch(void* const* d_in, const int* in_sizes, int n_in,
                              void* d_out, int out_size, void* d_ws, size_t ws_size,
                              hipStream_t stream) {
    const float* query = (const float*)d_in[0];
    const float* key_  = (const float*)d_in[1];
    const float* value = (const float*)d_in[2];
    const float* mask  = (const float*)d_in[3];
    const float* Wq = (const float*)d_in[4];
    const float* bq = (const float*)d_in[5];
    const float* Wk = (const float*)d_in[6];
    const float* bk = (const float*)d_in[7];
    const float* Wv = (const float*)d_in[8];
    const float* bv = (const float*)d_in[9];
    const float* Wo = (const float*)d_in[10];
    const float* bo = (const float*)d_in[11];
    float* out = (float*)d_out;

    const size_t NP = (size_t)BATCH * SEQ * DMODEL;   // 4194304
    unsigned short* ws   = (unsigned short*)d_ws;
    unsigned short* qb16 = ws;
    unsigned short* kb16 = qb16 + NP;
    unsigned short* vT16 = kb16 + NP;
    unsigned short* xb16 = vT16 + NP;
    unsigned short* em16 = xb16 + NP;                 // SEQ*SEQ f16
    unsigned short* Xp16 = em16 + (size_t)SEQ * SEQ;  // KSPLIT*NROWS*64 f16
    unsigned short* WqT  = Xp16 + (size_t)KSPLIT * NROWS * HDIM;
    unsigned short* WkT  = WqT + DMODEL * DMODEL;
    unsigned short* WvT  = WkT + DMODEL * DMODEL;
    unsigned short* WoT  = WvT + DMODEL * DMODEL;
    float* Lp = (float*)(WoT + DMODEL * DMODEL);      // KSPLIT*NROWS f32
    // total ws ~= 61 MB (same as round 7, known-safe)

    transpose_cast_w<<<dim3(16, 16, 4), 256, 0, stream>>>(
        Wq, Wk, Wv, Wo, WqT, WkT, WvT, WoT);
    prep_mask<<<dim3(SEQ / 64, SEQ / 16), 256, 0, stream>>>(mask, em16);

    QKVArgs qa;
    qa.A0 = query; qa.A1 = key_; qa.A2 = value;
    qa.W0 = WqT;   qa.W1 = WkT;  qa.W2 = WvT;
    qa.b0 = bq;    qa.b1 = bk;   qa.b2 = bv;
    qa.o0 = qb16;  qa.o1 = kb16; qa.o2 = vT16;   // V written transposed
    gemm_qkv<<<dim3(DMODEL / 128, BATCH * SEQ / 128, 3), 256, 0, stream>>>(qa);

    attn6<<<dim3(BATCH * NHEAD, SEQ / 128, KSPLIT), 256, 0, stream>>>(
        qb16, kb16, vT16, em16, Xp16, Lp);

    combine_attn<<<dim3(NROWS * 8 / 256), 256, 0, stream>>>(Xp16, Lp, xb16);

    gemm_fin<<<dim3(DMODEL / 128, BATCH * SEQ / 64), 256, 0, stream>>>(
        xb16, WoT, bo, out);
}